// Round 1
// baseline (284.921 us; speedup 1.0000x reference)
//
#include <hip/hip_runtime.h>
#include <stdint.h>

typedef int   i32x4 __attribute__((ext_vector_type(4)));
typedef float f32x4 __attribute__((ext_vector_type(4)));

// ---------------- workspace layout (bytes) ----------------
#define WS_SLOTS   0                         // 3 x u32 max-abs bits (memset 0)
#define WS_SCALES  64                        // 8 floats
#define WS_B1Q     128                       // 4096 int16
#define WS_B2Q     (128 + 8192)              // 1024 int16
#define WS_XQ      16384                     // 4 MB  int8 swizzled [32][16][4][128][16]
#define WS_W1QT    (WS_XQ   + 4096*1024)     // 4 MB  w1^T swizzled [32][16][4][128][16]
#define WS_W2QT    (WS_W1QT + 4096*1024)     // 4 MB  w2^T swizzled [8][64][4][128][16]
#define WS_PS      (WS_W2QT + 4096*1024)     // 16 MB plane_s swizzled [32][64][4][128][16]
#define WS_PH      (WS_PS   + 4096*4096)     // 16 MB plane_h
// total ~46.2 MB

__device__ __forceinline__ void async16(const void* g, void* l) {
  __builtin_amdgcn_global_load_lds(
      (const __attribute__((address_space(1))) unsigned*)g,
      (__attribute__((address_space(3))) unsigned*)l, 16, 0, 0);
}

// ---------------- abs-max reduction ----------------
__global__ void k_absmax(const float* __restrict__ p, int n4, unsigned* slot) {
  int i = blockIdx.x * blockDim.x + threadIdx.x;
  int stride = gridDim.x * blockDim.x;
  float m = 0.f;
  for (int j = i; j < n4; j += stride) {
    f32x4 v = ((const f32x4*)p)[j];
    m = fmaxf(m, fmaxf(fmaxf(fabsf(v.x), fabsf(v.y)), fmaxf(fabsf(v.z), fabsf(v.w))));
  }
  for (int off = 32; off; off >>= 1) m = fmaxf(m, __shfl_down(m, off));
  if ((threadIdx.x & 63) == 0) atomicMax(slot, __float_as_uint(m));
}

// ---------------- scales + bias quantization ----------------
__global__ void k_finalize(const unsigned* __restrict__ slots, float* __restrict__ scales,
                           const float* __restrict__ b1f, const float* __restrict__ b2f,
                           short* __restrict__ b1q, short* __restrict__ b2q) {
  float sx = __uint_as_float(slots[0]) / 127.0f;
  float s1 = __uint_as_float(slots[1]) / 127.0f;
  float s2 = __uint_as_float(slots[2]) / 127.0f;
  int tid = threadIdx.x;
  if (tid == 0) {
    scales[0] = sx; scales[1] = s1; scales[2] = s2;
    scales[3] = sx * s1 / s1;   // mult1, computed exactly as reference f32 expr
    scales[4] = s1 * s2 / s2;   // mult2
    scales[5] = s2;
  }
  for (int i = tid; i < 4096; i += blockDim.x) b1q[i] = (short)(int)rintf(b1f[i] / s1);
  for (int i = tid; i < 1024; i += blockDim.x) b2q[i] = (short)(int)rintf(b2f[i] / s2);
}

// ---------------- quantize x -> swizzled int8 [32][16][4][128][16] ----------------
__global__ void k_quant_x(const float* __restrict__ x, const float* __restrict__ scales,
                          i32x4* __restrict__ out) {
  int L = blockIdx.x * 256 + threadIdx.x;          // 256K chunks
  float s = scales[0];
  int m_in = L & 127, kb = (L >> 7) & 3, tk = (L >> 9) & 15, mblk = L >> 13;
  int m = mblk * 128 + m_in;
  int k0 = (tk * 4 + kb) * 16;
  const f32x4* px = (const f32x4*)(x + m * 1024 + k0);
  int wd[4];
  #pragma unroll
  for (int d = 0; d < 4; d++) {
    f32x4 v = px[d];
    int b0 = (int)rintf(v.x / s) & 255;
    int b1 = (int)rintf(v.y / s) & 255;
    int b2 = (int)rintf(v.z / s) & 255;
    int b3 = (int)rintf(v.w / s) & 255;
    wd[d] = b0 | (b1 << 8) | (b2 << 16) | (b3 << 24);
  }
  i32x4 o; o.x = wd[0]; o.y = wd[1]; o.z = wd[2]; o.w = wd[3];
  out[L] = o;
}

// ---------------- quantize + transpose weights -> swizzled int8 ----------------
// input [R][C] f32 row-major; output = quantized transpose [C][R] in swizzled layout
__global__ void k_quantT(const float* __restrict__ w, const float* __restrict__ scales,
                         int sidx, i32x4* __restrict__ out, int C, int tkbits) {
  int L = blockIdx.x * 256 + threadIdx.x;
  float s = scales[sidx];
  int h_in = L & 127;
  int kb = (L >> 7) & 3;
  int tk = (L >> 9) & ((1 << tkbits) - 1);
  int hblk = L >> (9 + tkbits);
  int h = hblk * 128 + h_in;
  int k0 = (tk * 4 + kb) * 16;
  int wd[4];
  #pragma unroll
  for (int d = 0; d < 4; d++) {
    unsigned acc = 0;
    #pragma unroll
    for (int j = 0; j < 4; j++) {
      float v = w[(size_t)(k0 + d * 4 + j) * C + h];   // coalesced across lanes (h contiguous)
      int q = (int)rintf(v / s) & 255;
      acc |= (unsigned)q << (8 * j);
    }
    wd[d] = (int)acc;
  }
  i32x4 o; o.x = wd[0]; o.y = wd[1]; o.z = wd[2]; o.w = wd[3];
  out[L] = o;
}

// ---------------- GEMM1 (transposed): o1^T tiles = w1q^T · x_q^T ----------------
// A' = w1qt swizzled [hblk][t16][kb][h_in][16], B' = xq swizzled [mblk][t16][kb][m_in][16]
// epilogue: requant + bias + relu + 256-split, dword-packed coalesced stores into planes
__launch_bounds__(256)
__global__ void k_gemm1(const i32x4* __restrict__ Aq, const i32x4* __restrict__ Bq,
                        const float* __restrict__ scales, const short* __restrict__ b1q,
                        unsigned* __restrict__ plane_s, unsigned* __restrict__ plane_h) {
  __shared__ i32x4 As[512];   // [kb][128]
  __shared__ i32x4 Bs[512];
  int tid = threadIdx.x;
  int bb = blockIdx.x;   // batch block (cols of o1^T), 0..31
  int hb = blockIdx.y;   // H block (rows of o1^T), 0..31
  int lane = tid & 63, wid = tid >> 6;
  int wm = wid & 1, wn = wid >> 1;
  int g = lane >> 4, l15 = lane & 15;

  i32x4 acc[4][4];
  #pragma unroll
  for (int r = 0; r < 4; r++)
    #pragma unroll
    for (int c = 0; c < 4; c++) acc[r][c] = (i32x4)(0);

  int abase = g * 128 + wm * 64 + l15;
  int bbase = g * 128 + wn * 64 + l15;

  for (int t = 0; t < 16; ++t) {
    const i32x4* ga = Aq + (hb * 16 + t) * 512;
    const i32x4* gb = Bq + (bb * 16 + t) * 512;
    async16(ga + tid, &As[tid]);
    async16(ga + tid + 256, &As[tid + 256]);
    async16(gb + tid, &Bs[tid]);
    async16(gb + tid + 256, &Bs[tid + 256]);
    __syncthreads();
    i32x4 af[4], bf[4];
    #pragma unroll
    for (int r = 0; r < 4; r++) af[r] = As[abase + r * 16];
    #pragma unroll
    for (int c = 0; c < 4; c++) bf[c] = Bs[bbase + c * 16];
    #pragma unroll
    for (int r = 0; r < 4; r++)
      #pragma unroll
      for (int c = 0; c < 4; c++)
        acc[r][c] = __builtin_amdgcn_mfma_i32_16x16x64_i8(af[r], bf[c], acc[r][c], 0, 0, 0);
    __syncthreads();
  }

  float mult1 = scales[3];
  int t2base = hb * 2 + wm;                 // h_abs>>6 (uniform per wave)
  #pragma unroll
  for (int r = 0; r < 4; r++) {
    int hbase = hb * 128 + wm * 64 + r * 16 + 4 * g;
    const short* bp = b1q + hbase;
    short bq0 = bp[0], bq1 = bp[1], bq2 = bp[2], bq3 = bp[3];
    #pragma unroll
    for (int c = 0; c < 4; c++) {
      unsigned lo = 0, hi = 0;
      #pragma unroll
      for (int q = 0; q < 4; q++) {
        int y0 = acc[r][c][q];
        short bqv = (q == 0) ? bq0 : (q == 1) ? bq1 : (q == 2) ? bq2 : bq3;
        int o = (short)((int)rintf((float)y0 * mult1) + (int)bqv);   // int16 semantics
        int a = o > 0 ? o : 0;                                       // relu
        int s8 = (int)(signed char)(a & 0xFF);
        int h8 = (a >> 8) + (s8 < 0 ? 1 : 0);                        // a = 256*h8 + s8 exactly
        lo |= (unsigned)(s8 & 0xFF) << (8 * q);
        hi |= (unsigned)(h8 & 0xFF) << (8 * q);
      }
      int m_in = wn * 64 + c * 16 + l15;
      unsigned idx = (((unsigned)(bb * 64 + t2base) * 512u + (unsigned)(r * 128 + m_in)) << 2) + g;
      plane_s[idx] = lo;
      plane_h[idx] = hi;
    }
  }
}

// ---------------- GEMM2: out = dequant(requant(relu(o1) @ w2q) + b2q) ----------------
// A planes swizzled [mblk][t64][kb][m_in][16], B = w2qt swizzled [nblk][t64][kb][n_in][16]
__launch_bounds__(256)
__global__ void k_gemm2(const i32x4* __restrict__ Ps, const i32x4* __restrict__ Ph,
                        const i32x4* __restrict__ Bq, const float* __restrict__ scales,
                        const short* __restrict__ b2q, float* __restrict__ out) {
  __shared__ i32x4 AsS[512];
  __shared__ i32x4 AsH[512];
  __shared__ i32x4 Bs[512];
  int tid = threadIdx.x;
  int nb = blockIdx.x;   // 0..7
  int mb = blockIdx.y;   // 0..31
  int lane = tid & 63, wid = tid >> 6;
  int wm = wid & 1, wn = wid >> 1;
  int g = lane >> 4, l15 = lane & 15;

  i32x4 accS[4][4], accH[4][4];
  #pragma unroll
  for (int r = 0; r < 4; r++)
    #pragma unroll
    for (int c = 0; c < 4; c++) { accS[r][c] = (i32x4)(0); accH[r][c] = (i32x4)(0); }

  int abase = g * 128 + wm * 64 + l15;
  int bbase = g * 128 + wn * 64 + l15;

  for (int t = 0; t < 64; ++t) {
    const i32x4* gs = Ps + (mb * 64 + t) * 512;
    const i32x4* gh = Ph + (mb * 64 + t) * 512;
    const i32x4* gb = Bq + (nb * 64 + t) * 512;
    async16(gs + tid, &AsS[tid]);
    async16(gs + tid + 256, &AsS[tid + 256]);
    async16(gh + tid, &AsH[tid]);
    async16(gh + tid + 256, &AsH[tid + 256]);
    async16(gb + tid, &Bs[tid]);
    async16(gb + tid + 256, &Bs[tid + 256]);
    __syncthreads();
    i32x4 aS[4], aH[4], bf[4];
    #pragma unroll
    for (int r = 0; r < 4; r++) { aS[r] = AsS[abase + r * 16]; aH[r] = AsH[abase + r * 16]; }
    #pragma unroll
    for (int c = 0; c < 4; c++) bf[c] = Bs[bbase + c * 16];
    #pragma unroll
    for (int r = 0; r < 4; r++)
      #pragma unroll
      for (int c = 0; c < 4; c++) {
        accS[r][c] = __builtin_amdgcn_mfma_i32_16x16x64_i8(aS[r], bf[c], accS[r][c], 0, 0, 0);
        accH[r][c] = __builtin_amdgcn_mfma_i32_16x16x64_i8(aH[r], bf[c], accH[r][c], 0, 0, 0);
      }
    __syncthreads();
  }

  float mult2 = scales[4];
  float s2 = scales[5];
  #pragma unroll
  for (int r = 0; r < 4; r++) {
    int m0 = mb * 128 + wm * 64 + r * 16 + 4 * g;
    #pragma unroll
    for (int c = 0; c < 4; c++) {
      int n = nb * 128 + wn * 64 + c * 16 + l15;
      int bqv = (int)b2q[n];
      #pragma unroll
      for (int q = 0; q < 4; q++) {
        int y0 = accS[r][c][q] + accH[r][c][q] * 256;
        int o = (short)((int)rintf((float)y0 * mult2) + bqv);   // int16 semantics
        out[(size_t)(m0 + q) * 1024 + n] = (float)o * s2;
      }
    }
  }
}

extern "C" void kernel_launch(void* const* d_in, const int* in_sizes, int n_in,
                              void* d_out, int out_size, void* d_ws, size_t ws_size,
                              hipStream_t stream) {
  const float* x   = (const float*)d_in[0];
  const float* w1f = (const float*)d_in[1];
  const float* b1f = (const float*)d_in[2];
  const float* w2f = (const float*)d_in[3];
  const float* b2f = (const float*)d_in[4];
  float* out = (float*)d_out;

  char* ws = (char*)d_ws;
  unsigned* slots = (unsigned*)(ws + WS_SLOTS);
  float*  scales  = (float*)(ws + WS_SCALES);
  short*  b1q     = (short*)(ws + WS_B1Q);
  short*  b2q     = (short*)(ws + WS_B2Q);
  i32x4*  xq      = (i32x4*)(ws + WS_XQ);
  i32x4*  w1qt    = (i32x4*)(ws + WS_W1QT);
  i32x4*  w2qt    = (i32x4*)(ws + WS_W2QT);
  unsigned* ps    = (unsigned*)(ws + WS_PS);
  unsigned* ph    = (unsigned*)(ws + WS_PH);

  hipMemsetAsync(ws, 0, 128, stream);
  k_absmax<<<512, 256, 0, stream>>>(x,   4096 * 1024 / 4, slots + 0);
  k_absmax<<<512, 256, 0, stream>>>(w1f, 1024 * 4096 / 4, slots + 1);
  k_absmax<<<4,   256, 0, stream>>>(b1f, 4096 / 4,        slots + 1);
  k_absmax<<<512, 256, 0, stream>>>(w2f, 4096 * 1024 / 4, slots + 2);
  k_absmax<<<1,   256, 0, stream>>>(b2f, 1024 / 4,        slots + 2);
  k_finalize<<<1, 256, 0, stream>>>(slots, scales, b1f, b2f, b1q, b2q);
  k_quant_x<<<1024, 256, 0, stream>>>(x, scales, xq);
  k_quantT<<<1024, 256, 0, stream>>>(w1f, scales, 1, w1qt, 4096, 4);
  k_quantT<<<1024, 256, 0, stream>>>(w2f, scales, 2, w2qt, 1024, 6);
  k_gemm1<<<dim3(32, 32), 256, 0, stream>>>(w1qt, xq, scales, b1q, ps, ph);
  k_gemm2<<<dim3(8, 32), 256, 0, stream>>>((const i32x4*)ps, (const i32x4*)ph, w2qt,
                                           scales, b2q, out);
}

// Round 2
// 258.664 us; speedup vs baseline: 1.1015x; 1.1015x over previous
//
#include <hip/hip_runtime.h>
#include <stdint.h>

typedef int   i32x4 __attribute__((ext_vector_type(4)));
typedef float f32x4 __attribute__((ext_vector_type(4)));

// ---------------- workspace layout (bytes) ----------------
#define WS_SLOTS   0                         // 3 x u32 max-abs bits (memset 0)
#define WS_SCALES  64                        // 8 floats
#define WS_B1Q     128                       // 4096 int16
#define WS_B2Q     (128 + 8192)              // 1024 int16
#define WS_XQ      16384                     // 4 MB  int8 swizzled [32][16][4][128][16]
#define WS_W1QT    (WS_XQ   + 4096*1024)     // 4 MB  w1^T swizzled [32][16][4][128][16]
#define WS_W2QT    (WS_W1QT + 4096*1024)     // 4 MB  w2^T swizzled [8][64][4][128][16]
#define WS_PS      (WS_W2QT + 4096*1024)     // 16 MB plane_s swizzled [32][64][4][128][16]
#define WS_PH      (WS_PS   + 4096*4096)     // 16 MB plane_h
// total ~46.2 MB

__device__ __forceinline__ void async16(const void* g, void* l) {
  __builtin_amdgcn_global_load_lds(
      (const __attribute__((address_space(1))) unsigned*)g,
      (__attribute__((address_space(3))) unsigned*)l, 16, 0, 0);
}

// ---------------- fused abs-max over x, w1f, w2f (each 4M f32) ----------------
__global__ void k_absmax3(const float* __restrict__ x, const float* __restrict__ w1,
                          const float* __restrict__ w2, unsigned* __restrict__ slots) {
  int seg = blockIdx.x >> 9;              // 0,1,2
  int b = blockIdx.x & 511;
  const float* p = (seg == 0) ? x : (seg == 1) ? w1 : w2;
  int i = b * 256 + threadIdx.x;          // stride 131072, n4 = 1048576 -> 8 iters
  float m = 0.f;
  #pragma unroll
  for (int it = 0; it < 8; it++) {
    f32x4 v = ((const f32x4*)p)[i + it * 131072];
    m = fmaxf(m, fmaxf(fmaxf(fabsf(v.x), fabsf(v.y)), fmaxf(fabsf(v.z), fabsf(v.w))));
  }
  for (int off = 32; off; off >>= 1) m = fmaxf(m, __shfl_down(m, off));
  if ((threadIdx.x & 63) == 0) atomicMax(slots + seg, __float_as_uint(m));
}

// ---------------- scales (incl. bias absmax) + bias quantization ----------------
__global__ void k_finalize(const unsigned* __restrict__ slots, float* __restrict__ scales,
                           const float* __restrict__ b1f, const float* __restrict__ b2f,
                           short* __restrict__ b1q, short* __restrict__ b2q) {
  __shared__ float red[8];
  __shared__ float sh_s1, sh_s2;
  int tid = threadIdx.x;
  float m1 = 0.f, m2 = 0.f;
  for (int i = tid; i < 4096; i += 256) m1 = fmaxf(m1, fabsf(b1f[i]));
  for (int i = tid; i < 1024; i += 256) m2 = fmaxf(m2, fabsf(b2f[i]));
  for (int off = 32; off; off >>= 1) {
    m1 = fmaxf(m1, __shfl_down(m1, off));
    m2 = fmaxf(m2, __shfl_down(m2, off));
  }
  if ((tid & 63) == 0) { red[tid >> 6] = m1; red[4 + (tid >> 6)] = m2; }
  __syncthreads();
  if (tid == 0) {
    float M1 = fmaxf(fmaxf(red[0], red[1]), fmaxf(red[2], red[3]));
    float M2 = fmaxf(fmaxf(red[4], red[5]), fmaxf(red[6], red[7]));
    float sx = __uint_as_float(slots[0]) / 127.0f;
    float s1 = fmaxf(__uint_as_float(slots[1]), M1) / 127.0f;
    float s2 = fmaxf(__uint_as_float(slots[2]), M2) / 127.0f;
    scales[0] = sx; scales[1] = s1; scales[2] = s2;
    scales[3] = sx * s1 / s1;   // mult1, exact f32 expr as reference
    scales[4] = s1 * s2 / s2;   // mult2
    scales[5] = s2;
    sh_s1 = s1; sh_s2 = s2;
  }
  __syncthreads();
  float s1 = sh_s1, s2 = sh_s2;
  for (int i = tid; i < 4096; i += 256) b1q[i] = (short)(int)rintf(b1f[i] / s1);
  for (int i = tid; i < 1024; i += 256) b2q[i] = (short)(int)rintf(b2f[i] / s2);
}

// ---------------- quantize x -> swizzled int8 [32][16][4][128][16] ----------------
__global__ void k_quant_x(const float* __restrict__ x, const float* __restrict__ scales,
                          i32x4* __restrict__ out) {
  int L = blockIdx.x * 256 + threadIdx.x;
  float s = scales[0];
  int m_in = L & 127, kb = (L >> 7) & 3, tk = (L >> 9) & 15, mblk = L >> 13;
  int m = mblk * 128 + m_in;
  int k0 = (tk * 4 + kb) * 16;
  const f32x4* px = (const f32x4*)(x + m * 1024 + k0);
  int wd[4];
  #pragma unroll
  for (int d = 0; d < 4; d++) {
    f32x4 v = px[d];
    int b0 = (int)rintf(v.x / s) & 255;
    int b1 = (int)rintf(v.y / s) & 255;
    int b2 = (int)rintf(v.z / s) & 255;
    int b3 = (int)rintf(v.w / s) & 255;
    wd[d] = b0 | (b1 << 8) | (b2 << 16) | (b3 << 24);
  }
  i32x4 o; o.x = wd[0]; o.y = wd[1]; o.z = wd[2]; o.w = wd[3];
  out[L] = o;
}

// ---------------- quantize + transpose weights -> swizzled int8 ----------------
__global__ void k_quantT(const float* __restrict__ w, const float* __restrict__ scales,
                         int sidx, i32x4* __restrict__ out, int C, int tkbits) {
  int L = blockIdx.x * 256 + threadIdx.x;
  float s = scales[sidx];
  int h_in = L & 127;
  int kb = (L >> 7) & 3;
  int tk = (L >> 9) & ((1 << tkbits) - 1);
  int hblk = L >> (9 + tkbits);
  int h = hblk * 128 + h_in;
  int k0 = (tk * 4 + kb) * 16;
  int wd[4];
  #pragma unroll
  for (int d = 0; d < 4; d++) {
    unsigned acc = 0;
    #pragma unroll
    for (int j = 0; j < 4; j++) {
      float v = w[(size_t)(k0 + d * 4 + j) * C + h];
      int q = (int)rintf(v / s) & 255;
      acc |= (unsigned)q << (8 * j);
    }
    wd[d] = (int)acc;
  }
  i32x4 o; o.x = wd[0]; o.y = wd[1]; o.z = wd[2]; o.w = wd[3];
  out[L] = o;
}

// ---------------- GEMM1 (transposed, double-buffered): o1^T = w1q^T · x_q^T ----------------
__launch_bounds__(256)
__global__ void k_gemm1(const i32x4* __restrict__ Aq, const i32x4* __restrict__ Bq,
                        const float* __restrict__ scales, const short* __restrict__ b1q,
                        unsigned* __restrict__ plane_s, unsigned* __restrict__ plane_h) {
  __shared__ i32x4 As[2][512];   // [buf][kb4][row128]
  __shared__ i32x4 Bs[2][512];
  int tid = threadIdx.x;
  int bb = blockIdx.x;   // batch block, 0..31
  int hb = blockIdx.y;   // H block,    0..31
  int lane = tid & 63, wid = tid >> 6;
  int wm = wid & 1, wn = wid >> 1;
  int g = lane >> 4, l15 = lane & 15;

  i32x4 acc[4][4];
  #pragma unroll
  for (int r = 0; r < 4; r++)
    #pragma unroll
    for (int c = 0; c < 4; c++) acc[r][c] = (i32x4)(0);

  int abase = g * 128 + wm * 64 + l15;
  int bbase = g * 128 + wn * 64 + l15;

  const i32x4* gA = Aq + (size_t)hb * 16 * 512;
  const i32x4* gB = Bq + (size_t)bb * 16 * 512;

  // prefetch tile 0 into buf 0
  async16(gA + tid, &As[0][tid]);
  async16(gA + tid + 256, &As[0][tid + 256]);
  async16(gB + tid, &Bs[0][tid]);
  async16(gB + tid + 256, &Bs[0][tid + 256]);

  for (int t = 0; t < 16; ++t) {
    int cur = t & 1;
    __syncthreads();                       // drains stage(t); syncs buf reuse
    if (t + 1 < 16) {                      // prefetch t+1 into the other buffer
      const i32x4* ga = gA + (t + 1) * 512;
      const i32x4* gb = gB + (t + 1) * 512;
      async16(ga + tid, &As[cur ^ 1][tid]);
      async16(ga + tid + 256, &As[cur ^ 1][tid + 256]);
      async16(gb + tid, &Bs[cur ^ 1][tid]);
      async16(gb + tid + 256, &Bs[cur ^ 1][tid + 256]);
    }
    i32x4 af[4], bf[4];
    #pragma unroll
    for (int r = 0; r < 4; r++) af[r] = As[cur][abase + r * 16];
    #pragma unroll
    for (int c = 0; c < 4; c++) bf[c] = Bs[cur][bbase + c * 16];
    #pragma unroll
    for (int r = 0; r < 4; r++)
      #pragma unroll
      for (int c = 0; c < 4; c++)
        acc[r][c] = __builtin_amdgcn_mfma_i32_16x16x64_i8(af[r], bf[c], acc[r][c], 0, 0, 0);
  }

  float mult1 = scales[3];
  int t2base = hb * 2 + wm;
  #pragma unroll
  for (int r = 0; r < 4; r++) {
    int hbase = hb * 128 + wm * 64 + r * 16 + 4 * g;
    const short* bp = b1q + hbase;
    short bq0 = bp[0], bq1 = bp[1], bq2 = bp[2], bq3 = bp[3];
    #pragma unroll
    for (int c = 0; c < 4; c++) {
      unsigned lo = 0, hi = 0;
      #pragma unroll
      for (int q = 0; q < 4; q++) {
        int y0 = acc[r][c][q];
        short bqv = (q == 0) ? bq0 : (q == 1) ? bq1 : (q == 2) ? bq2 : bq3;
        int o = (short)((int)rintf((float)y0 * mult1) + (int)bqv);   // int16 semantics
        int a = o > 0 ? o : 0;                                       // relu
        int s8 = (int)(signed char)(a & 0xFF);
        int h8 = (a >> 8) + (s8 < 0 ? 1 : 0);                        // a = 256*h8 + s8
        lo |= (unsigned)(s8 & 0xFF) << (8 * q);
        hi |= (unsigned)(h8 & 0xFF) << (8 * q);
      }
      int m_in = wn * 64 + c * 16 + l15;
      unsigned idx = (((unsigned)(bb * 64 + t2base) * 512u + (unsigned)(r * 128 + m_in)) << 2) + g;
      plane_s[idx] = lo;
      plane_h[idx] = hi;
    }
  }
}

// ---------------- GEMM2 (64x128 tiles, double-buffered) ----------------
// A planes swizzled [mblk128][t64][kb4][m_in128][16], B = w2qt [nblk][t64][kb4][n_in128][16]
__launch_bounds__(256)
__global__ void k_gemm2(const i32x4* __restrict__ Ps, const i32x4* __restrict__ Ph,
                        const i32x4* __restrict__ Bq, const float* __restrict__ scales,
                        const short* __restrict__ b2q, float* __restrict__ out) {
  __shared__ i32x4 AsS[2][256];   // [buf][kb4][row64]
  __shared__ i32x4 AsH[2][256];
  __shared__ i32x4 Bs[2][512];    // [buf][kb4][row128]
  int tid = threadIdx.x;
  int L = blockIdx.x;
  int mb = L & 63;               // 64-row tile; mb%8 == L%8 -> same-XCD A-strip sharing
  int nb = L >> 6;               // 0..7
  int mblk = mb >> 1, half = mb & 1;
  int lane = tid & 63, wid = tid >> 6;
  int wm = wid & 1, wn = wid >> 1;
  int g = lane >> 4, l15 = lane & 15;

  i32x4 accS[2][4], accH[2][4];
  #pragma unroll
  for (int r = 0; r < 2; r++)
    #pragma unroll
    for (int c = 0; c < 4; c++) { accS[r][c] = (i32x4)(0); accH[r][c] = (i32x4)(0); }

  int aoff = wid * 128 + half * 64 + lane;   // global offset within A t-tile (kb=wid... wid<4)
  int abase = g * 64 + wm * 32 + l15;        // LDS frag base [kb4][row64]
  int bbase = g * 128 + wn * 64 + l15;

  const i32x4* gS = Ps + (size_t)mblk * 64 * 512;
  const i32x4* gH = Ph + (size_t)mblk * 64 * 512;
  const i32x4* gB = Bq + (size_t)nb * 64 * 512;

  // prefetch tile 0 into buf 0
  async16(gS + aoff, &AsS[0][tid]);
  async16(gH + aoff, &AsH[0][tid]);
  async16(gB + tid, &Bs[0][tid]);
  async16(gB + tid + 256, &Bs[0][tid + 256]);

  for (int t = 0; t < 64; ++t) {
    int cur = t & 1;
    __syncthreads();
    if (t + 1 < 64) {
      const i32x4* gs = gS + (t + 1) * 512;
      const i32x4* gh = gH + (t + 1) * 512;
      const i32x4* gb = gB + (t + 1) * 512;
      async16(gs + aoff, &AsS[cur ^ 1][tid]);
      async16(gh + aoff, &AsH[cur ^ 1][tid]);
      async16(gb + tid, &Bs[cur ^ 1][tid]);
      async16(gb + tid + 256, &Bs[cur ^ 1][tid + 256]);
    }
    i32x4 aS[2], aH[2], bf[4];
    #pragma unroll
    for (int r = 0; r < 2; r++) {
      aS[r] = AsS[cur][abase + r * 16];
      aH[r] = AsH[cur][abase + r * 16];
    }
    #pragma unroll
    for (int c = 0; c < 4; c++) bf[c] = Bs[cur][bbase + c * 16];
    #pragma unroll
    for (int r = 0; r < 2; r++)
      #pragma unroll
      for (int c = 0; c < 4; c++) {
        accS[r][c] = __builtin_amdgcn_mfma_i32_16x16x64_i8(aS[r], bf[c], accS[r][c], 0, 0, 0);
        accH[r][c] = __builtin_amdgcn_mfma_i32_16x16x64_i8(aH[r], bf[c], accH[r][c], 0, 0, 0);
      }
  }

  float mult2 = scales[4];
  float s2 = scales[5];
  #pragma unroll
  for (int r = 0; r < 2; r++) {
    int m0 = mb * 64 + wm * 32 + r * 16 + 4 * g;
    #pragma unroll
    for (int c = 0; c < 4; c++) {
      int n = nb * 128 + wn * 64 + c * 16 + l15;
      int bqv = (int)b2q[n];
      #pragma unroll
      for (int q = 0; q < 4; q++) {
        int y0 = accS[r][c][q] + accH[r][c][q] * 256;
        int o = (short)((int)rintf((float)y0 * mult2) + bqv);   // int16 semantics
        out[(size_t)(m0 + q) * 1024 + n] = (float)o * s2;
      }
    }
  }
}

extern "C" void kernel_launch(void* const* d_in, const int* in_sizes, int n_in,
                              void* d_out, int out_size, void* d_ws, size_t ws_size,
                              hipStream_t stream) {
  const float* x   = (const float*)d_in[0];
  const float* w1f = (const float*)d_in[1];
  const float* b1f = (const float*)d_in[2];
  const float* w2f = (const float*)d_in[3];
  const float* b2f = (const float*)d_in[4];
  float* out = (float*)d_out;

  char* ws = (char*)d_ws;
  unsigned* slots = (unsigned*)(ws + WS_SLOTS);
  float*  scales  = (float*)(ws + WS_SCALES);
  short*  b1q     = (short*)(ws + WS_B1Q);
  short*  b2q     = (short*)(ws + WS_B2Q);
  i32x4*  xq      = (i32x4*)(ws + WS_XQ);
  i32x4*  w1qt    = (i32x4*)(ws + WS_W1QT);
  i32x4*  w2qt    = (i32x4*)(ws + WS_W2QT);
  unsigned* ps    = (unsigned*)(ws + WS_PS);
  unsigned* ph    = (unsigned*)(ws + WS_PH);

  hipMemsetAsync(ws, 0, 128, stream);
  k_absmax3<<<1536, 256, 0, stream>>>(x, w1f, w2f, slots);
  k_finalize<<<1, 256, 0, stream>>>(slots, scales, b1f, b2f, b1q, b2q);
  k_quant_x<<<1024, 256, 0, stream>>>(x, scales, xq);
  k_quantT<<<1024, 256, 0, stream>>>(w1f, scales, 1, w1qt, 4096, 4);
  k_quantT<<<1024, 256, 0, stream>>>(w2f, scales, 2, w2qt, 1024, 6);
  k_gemm1<<<dim3(32, 32), 256, 0, stream>>>(w1qt, xq, scales, b1q, ps, ph);
  k_gemm2<<<512, 256, 0, stream>>>((const i32x4*)ps, (const i32x4*)ph, w2qt,
                                   scales, b2q, out);
}

// Round 3
// 196.653 us; speedup vs baseline: 1.4489x; 1.3153x over previous
//
#include <hip/hip_runtime.h>
#include <stdint.h>

typedef int   i32x4 __attribute__((ext_vector_type(4)));
typedef float f32x4 __attribute__((ext_vector_type(4)));

// ---------------- workspace layout (bytes) ----------------
#define WS_PART    0                         // 1536 floats: per-block absmax partials
#define WS_SCALES  6144                      // 8 floats
#define WS_B1Q     6208                      // 4096 int16
#define WS_B2Q     (6208 + 8192)             // 1024 int16
#define WS_XQ      32768                     // 4 MB  int8 swizzled [32][16][4][128][16]
#define WS_W1QT    (WS_XQ   + 4096*1024)     // 4 MB  w1^T swizzled [32][16][4][128][16]
#define WS_W2QT    (WS_W1QT + 4096*1024)     // 4 MB  w2^T swizzled [8][64][4][128][16]
#define WS_PS      (WS_W2QT + 4096*1024)     // 16 MB plane_s swizzled [32][64][4][128][16]
#define WS_PH      (WS_PS   + 4096*4096)     // 16 MB plane_h
// total ~46.3 MB

__device__ __forceinline__ void async16(const void* g, void* l) {
  __builtin_amdgcn_global_load_lds(
      (const __attribute__((address_space(1))) unsigned*)g,
      (__attribute__((address_space(3))) unsigned*)l, 16, 0, 0);
}

// ---------------- fused abs-max over x, w1f, w2f: per-block partials, NO atomics ----------------
__global__ void k_absmax3(const float* __restrict__ x, const float* __restrict__ w1,
                          const float* __restrict__ w2, float* __restrict__ part) {
  int seg = blockIdx.x >> 9;              // 0,1,2
  int b = blockIdx.x & 511;
  const float* p = (seg == 0) ? x : (seg == 1) ? w1 : w2;
  int i = b * 256 + threadIdx.x;          // stride 131072 f32x4, n4 = 1048576 -> 8 iters
  float m = 0.f;
  #pragma unroll
  for (int it = 0; it < 8; it++) {
    f32x4 v = ((const f32x4*)p)[i + it * 131072];
    m = fmaxf(m, fmaxf(fmaxf(fabsf(v.x), fabsf(v.y)), fmaxf(fabsf(v.z), fabsf(v.w))));
  }
  for (int off = 32; off; off >>= 1) m = fmaxf(m, __shfl_down(m, off));
  __shared__ float red[4];
  if ((threadIdx.x & 63) == 0) red[threadIdx.x >> 6] = m;
  __syncthreads();
  if (threadIdx.x == 0)
    part[blockIdx.x] = fmaxf(fmaxf(red[0], red[1]), fmaxf(red[2], red[3]));
}

// ---------------- reduce partials + bias absmax -> scales; quantize biases ----------------
__global__ void k_finalize(const float* __restrict__ part, float* __restrict__ scales,
                           const float* __restrict__ b1f, const float* __restrict__ b2f,
                           short* __restrict__ b1q, short* __restrict__ b2q) {
  __shared__ float red[12];
  __shared__ float sh[2];
  int tid = threadIdx.x;
  float mx = 0.f, m1 = 0.f, m2 = 0.f;
  #pragma unroll
  for (int i = 0; i < 2; i++) {
    int j = tid + i * 256;
    mx = fmaxf(mx, part[j]);
    m1 = fmaxf(m1, part[512 + j]);
    m2 = fmaxf(m2, part[1024 + j]);
  }
  for (int i = tid; i < 4096; i += 256) m1 = fmaxf(m1, fabsf(b1f[i]));   // joint w/b max
  for (int i = tid; i < 1024; i += 256) m2 = fmaxf(m2, fabsf(b2f[i]));
  for (int off = 32; off; off >>= 1) {
    mx = fmaxf(mx, __shfl_down(mx, off));
    m1 = fmaxf(m1, __shfl_down(m1, off));
    m2 = fmaxf(m2, __shfl_down(m2, off));
  }
  if ((tid & 63) == 0) {
    int w = tid >> 6;
    red[w] = mx; red[4 + w] = m1; red[8 + w] = m2;
  }
  __syncthreads();
  if (tid == 0) {
    float MX = fmaxf(fmaxf(red[0], red[1]), fmaxf(red[2], red[3]));
    float M1 = fmaxf(fmaxf(red[4], red[5]), fmaxf(red[6], red[7]));
    float M2 = fmaxf(fmaxf(red[8], red[9]), fmaxf(red[10], red[11]));
    float sx = MX / 127.0f;
    float s1 = M1 / 127.0f;
    float s2 = M2 / 127.0f;
    scales[0] = sx; scales[1] = s1; scales[2] = s2;
    scales[3] = sx * s1 / s1;   // mult1, exact f32 expr as reference
    scales[4] = s1 * s2 / s2;   // mult2
    scales[5] = s2;
    sh[0] = s1; sh[1] = s2;
  }
  __syncthreads();
  float s1 = sh[0], s2 = sh[1];
  for (int i = tid; i < 4096; i += 256) b1q[i] = (short)(int)rintf(b1f[i] / s1);
  for (int i = tid; i < 1024; i += 256) b2q[i] = (short)(int)rintf(b2f[i] / s2);
}

// ---------------- quantize x -> swizzled int8 [32][16][4][128][16] ----------------
__global__ void k_quant_x(const float* __restrict__ x, const float* __restrict__ scales,
                          i32x4* __restrict__ out) {
  int L = blockIdx.x * 256 + threadIdx.x;
  float s = scales[0];
  int m_in = L & 127, kb = (L >> 7) & 3, tk = (L >> 9) & 15, mblk = L >> 13;
  int m = mblk * 128 + m_in;
  int k0 = (tk * 4 + kb) * 16;
  const f32x4* px = (const f32x4*)(x + m * 1024 + k0);
  int wd[4];
  #pragma unroll
  for (int d = 0; d < 4; d++) {
    f32x4 v = px[d];
    int b0 = (int)rintf(v.x / s) & 255;
    int b1 = (int)rintf(v.y / s) & 255;
    int b2 = (int)rintf(v.z / s) & 255;
    int b3 = (int)rintf(v.w / s) & 255;
    wd[d] = b0 | (b1 << 8) | (b2 << 16) | (b3 << 24);
  }
  i32x4 o; o.x = wd[0]; o.y = wd[1]; o.z = wd[2]; o.w = wd[3];
  out[L] = o;
}

// ---------------- quantize + transpose weights -> swizzled int8 ----------------
__global__ void k_quantT(const float* __restrict__ w, const float* __restrict__ scales,
                         int sidx, i32x4* __restrict__ out, int C, int tkbits) {
  int L = blockIdx.x * 256 + threadIdx.x;
  float s = scales[sidx];
  int h_in = L & 127;
  int kb = (L >> 7) & 3;
  int tk = (L >> 9) & ((1 << tkbits) - 1);
  int hblk = L >> (9 + tkbits);
  int h = hblk * 128 + h_in;
  int k0 = (tk * 4 + kb) * 16;
  int wd[4];
  #pragma unroll
  for (int d = 0; d < 4; d++) {
    unsigned acc = 0;
    #pragma unroll
    for (int j = 0; j < 4; j++) {
      float v = w[(size_t)(k0 + d * 4 + j) * C + h];
      int q = (int)rintf(v / s) & 255;
      acc |= (unsigned)q << (8 * j);
    }
    wd[d] = (int)acc;
  }
  i32x4 o; o.x = wd[0]; o.y = wd[1]; o.z = wd[2]; o.w = wd[3];
  out[L] = o;
}

// ---------------- GEMM1 (transposed, double-buffered): o1^T = w1q^T · x_q^T ----------------
__launch_bounds__(256)
__global__ void k_gemm1(const i32x4* __restrict__ Aq, const i32x4* __restrict__ Bq,
                        const float* __restrict__ scales, const short* __restrict__ b1q,
                        unsigned* __restrict__ plane_s, unsigned* __restrict__ plane_h) {
  __shared__ i32x4 As[2][512];   // [buf][kb4][row128]
  __shared__ i32x4 Bs[2][512];
  int tid = threadIdx.x;
  int bb = blockIdx.x;   // batch block, 0..31
  int hb = blockIdx.y;   // H block,    0..31
  int lane = tid & 63, wid = tid >> 6;
  int wm = wid & 1, wn = wid >> 1;
  int g = lane >> 4, l15 = lane & 15;

  i32x4 acc[4][4];
  #pragma unroll
  for (int r = 0; r < 4; r++)
    #pragma unroll
    for (int c = 0; c < 4; c++) acc[r][c] = (i32x4)(0);

  int abase = g * 128 + wm * 64 + l15;
  int bbase = g * 128 + wn * 64 + l15;

  const i32x4* gA = Aq + (size_t)hb * 16 * 512;
  const i32x4* gB = Bq + (size_t)bb * 16 * 512;

  async16(gA + tid, &As[0][tid]);
  async16(gA + tid + 256, &As[0][tid + 256]);
  async16(gB + tid, &Bs[0][tid]);
  async16(gB + tid + 256, &Bs[0][tid + 256]);

  for (int t = 0; t < 16; ++t) {
    int cur = t & 1;
    __syncthreads();
    if (t + 1 < 16) {
      const i32x4* ga = gA + (t + 1) * 512;
      const i32x4* gb = gB + (t + 1) * 512;
      async16(ga + tid, &As[cur ^ 1][tid]);
      async16(ga + tid + 256, &As[cur ^ 1][tid + 256]);
      async16(gb + tid, &Bs[cur ^ 1][tid]);
      async16(gb + tid + 256, &Bs[cur ^ 1][tid + 256]);
    }
    i32x4 af[4], bf[4];
    #pragma unroll
    for (int r = 0; r < 4; r++) af[r] = As[cur][abase + r * 16];
    #pragma unroll
    for (int c = 0; c < 4; c++) bf[c] = Bs[cur][bbase + c * 16];
    #pragma unroll
    for (int r = 0; r < 4; r++)
      #pragma unroll
      for (int c = 0; c < 4; c++)
        acc[r][c] = __builtin_amdgcn_mfma_i32_16x16x64_i8(af[r], bf[c], acc[r][c], 0, 0, 0);
  }

  float mult1 = scales[3];
  int t2base = hb * 2 + wm;
  #pragma unroll
  for (int r = 0; r < 4; r++) {
    int hbase = hb * 128 + wm * 64 + r * 16 + 4 * g;
    const short* bp = b1q + hbase;
    short bq0 = bp[0], bq1 = bp[1], bq2 = bp[2], bq3 = bp[3];
    #pragma unroll
    for (int c = 0; c < 4; c++) {
      unsigned lo = 0, hi = 0;
      #pragma unroll
      for (int q = 0; q < 4; q++) {
        int y0 = acc[r][c][q];
        short bqv = (q == 0) ? bq0 : (q == 1) ? bq1 : (q == 2) ? bq2 : bq3;
        int o = (short)((int)rintf((float)y0 * mult1) + (int)bqv);   // int16 semantics
        int a = o > 0 ? o : 0;                                       // relu
        int s8 = (int)(signed char)(a & 0xFF);
        int h8 = (a >> 8) + (s8 < 0 ? 1 : 0);                        // a = 256*h8 + s8
        lo |= (unsigned)(s8 & 0xFF) << (8 * q);
        hi |= (unsigned)(h8 & 0xFF) << (8 * q);
      }
      int m_in = wn * 64 + c * 16 + l15;
      unsigned idx = (((unsigned)(bb * 64 + t2base) * 512u + (unsigned)(r * 128 + m_in)) << 2) + g;
      plane_s[idx] = lo;
      plane_h[idx] = hi;
    }
  }
}

// ---------------- GEMM2 (64x128 tiles, double-buffered) ----------------
__launch_bounds__(256)
__global__ void k_gemm2(const i32x4* __restrict__ Ps, const i32x4* __restrict__ Ph,
                        const i32x4* __restrict__ Bq, const float* __restrict__ scales,
                        const short* __restrict__ b2q, float* __restrict__ out) {
  __shared__ i32x4 AsS[2][256];   // [buf][kb4][row64]
  __shared__ i32x4 AsH[2][256];
  __shared__ i32x4 Bs[2][512];    // [buf][kb4][row128]
  int tid = threadIdx.x;
  int L = blockIdx.x;
  int mb = L & 63;               // mb%8 == L%8 -> same-XCD A-strip sharing
  int nb = L >> 6;               // 0..7
  int mblk = mb >> 1, half = mb & 1;
  int lane = tid & 63, wid = tid >> 6;
  int wm = wid & 1, wn = wid >> 1;
  int g = lane >> 4, l15 = lane & 15;

  i32x4 accS[2][4], accH[2][4];
  #pragma unroll
  for (int r = 0; r < 2; r++)
    #pragma unroll
    for (int c = 0; c < 4; c++) { accS[r][c] = (i32x4)(0); accH[r][c] = (i32x4)(0); }

  int aoff = wid * 128 + half * 64 + lane;
  int abase = g * 64 + wm * 32 + l15;
  int bbase = g * 128 + wn * 64 + l15;

  const i32x4* gS = Ps + (size_t)mblk * 64 * 512;
  const i32x4* gH = Ph + (size_t)mblk * 64 * 512;
  const i32x4* gB = Bq + (size_t)nb * 64 * 512;

  async16(gS + aoff, &AsS[0][tid]);
  async16(gH + aoff, &AsH[0][tid]);
  async16(gB + tid, &Bs[0][tid]);
  async16(gB + tid + 256, &Bs[0][tid + 256]);

  for (int t = 0; t < 64; ++t) {
    int cur = t & 1;
    __syncthreads();
    if (t + 1 < 64) {
      const i32x4* gs = gS + (t + 1) * 512;
      const i32x4* gh = gH + (t + 1) * 512;
      const i32x4* gb = gB + (t + 1) * 512;
      async16(gs + aoff, &AsS[cur ^ 1][tid]);
      async16(gh + aoff, &AsH[cur ^ 1][tid]);
      async16(gb + tid, &Bs[cur ^ 1][tid]);
      async16(gb + tid + 256, &Bs[cur ^ 1][tid + 256]);
    }
    i32x4 aS[2], aH[2], bf[4];
    #pragma unroll
    for (int r = 0; r < 2; r++) {
      aS[r] = AsS[cur][abase + r * 16];
      aH[r] = AsH[cur][abase + r * 16];
    }
    #pragma unroll
    for (int c = 0; c < 4; c++) bf[c] = Bs[cur][bbase + c * 16];
    #pragma unroll
    for (int r = 0; r < 2; r++)
      #pragma unroll
      for (int c = 0; c < 4; c++) {
        accS[r][c] = __builtin_amdgcn_mfma_i32_16x16x64_i8(aS[r], bf[c], accS[r][c], 0, 0, 0);
        accH[r][c] = __builtin_amdgcn_mfma_i32_16x16x64_i8(aH[r], bf[c], accH[r][c], 0, 0, 0);
      }
  }

  float mult2 = scales[4];
  float s2 = scales[5];
  #pragma unroll
  for (int r = 0; r < 2; r++) {
    int m0 = mb * 64 + wm * 32 + r * 16 + 4 * g;
    #pragma unroll
    for (int c = 0; c < 4; c++) {
      int n = nb * 128 + wn * 64 + c * 16 + l15;
      int bqv = (int)b2q[n];
      #pragma unroll
      for (int q = 0; q < 4; q++) {
        int y0 = accS[r][c][q] + accH[r][c][q] * 256;
        int o = (short)((int)rintf((float)y0 * mult2) + bqv);   // int16 semantics
        out[(size_t)(m0 + q) * 1024 + n] = (float)o * s2;
      }
    }
  }
}

extern "C" void kernel_launch(void* const* d_in, const int* in_sizes, int n_in,
                              void* d_out, int out_size, void* d_ws, size_t ws_size,
                              hipStream_t stream) {
  const float* x   = (const float*)d_in[0];
  const float* w1f = (const float*)d_in[1];
  const float* b1f = (const float*)d_in[2];
  const float* w2f = (const float*)d_in[3];
  const float* b2f = (const float*)d_in[4];
  float* out = (float*)d_out;

  char* ws = (char*)d_ws;
  float*  part    = (float*)(ws + WS_PART);
  float*  scales  = (float*)(ws + WS_SCALES);
  short*  b1q     = (short*)(ws + WS_B1Q);
  short*  b2q     = (short*)(ws + WS_B2Q);
  i32x4*  xq      = (i32x4*)(ws + WS_XQ);
  i32x4*  w1qt    = (i32x4*)(ws + WS_W1QT);
  i32x4*  w2qt    = (i32x4*)(ws + WS_W2QT);
  unsigned* ps    = (unsigned*)(ws + WS_PS);
  unsigned* ph    = (unsigned*)(ws + WS_PH);

  k_absmax3<<<1536, 256, 0, stream>>>(x, w1f, w2f, part);
  k_finalize<<<1, 256, 0, stream>>>(part, scales, b1f, b2f, b1q, b2q);
  k_quant_x<<<1024, 256, 0, stream>>>(x, scales, xq);
  k_quantT<<<1024, 256, 0, stream>>>(w1f, scales, 1, w1qt, 4096, 4);
  k_quantT<<<1024, 256, 0, stream>>>(w2f, scales, 2, w2qt, 1024, 6);
  k_gemm1<<<dim3(32, 32), 256, 0, stream>>>(w1qt, xq, scales, b1q, ps, ph);
  k_gemm2<<<512, 256, 0, stream>>>((const i32x4*)ps, (const i32x4*)ph, w2qt,
                                   scales, b2q, out);
}

// Round 4
// 178.299 us; speedup vs baseline: 1.5980x; 1.1029x over previous
//
#include <hip/hip_runtime.h>
#include <stdint.h>

typedef int   i32x4 __attribute__((ext_vector_type(4)));
typedef float f32x4 __attribute__((ext_vector_type(4)));

// ---------------- workspace layout (bytes) ----------------
#define WS_PART    0                         // 1536 floats: per-block absmax partials
#define WS_XQ      32768                     // 4 MB  int8 swizzled [32][16][4][128][16]
#define WS_W1QT    (WS_XQ   + 4096*1024)     // 4 MB  w1^T swizzled [32][16][4][128][16]
#define WS_W2QT    (WS_W1QT + 4096*1024)     // 4 MB  w2^T swizzled [8][64][4][128][16]
#define WS_PS      (WS_W2QT + 4096*1024)     // 16 MB plane_s swizzled [32][64][4][128][16]
#define WS_PH      (WS_PS   + 4096*4096)     // 16 MB plane_h

__device__ __forceinline__ void async16(const void* g, void* l) {
  __builtin_amdgcn_global_load_lds(
      (const __attribute__((address_space(1))) unsigned*)g,
      (__attribute__((address_space(3))) unsigned*)l, 16, 0, 0);
}

// block-wide absmax over p0[0..n0) and optional p1[0..n1); bit-exact in any order
__device__ __forceinline__ float block_absmax(const float* __restrict__ p0, int n0,
                                              const float* __restrict__ p1, int n1,
                                              float* red, float* slot) {
  int tid = threadIdx.x, nt = blockDim.x;
  float m = 0.f;
  for (int i = tid; i < n0; i += nt) m = fmaxf(m, fabsf(p0[i]));
  if (p1) for (int i = tid; i < n1; i += nt) m = fmaxf(m, fabsf(p1[i]));
  for (int off = 32; off; off >>= 1) m = fmaxf(m, __shfl_down(m, off));
  if ((tid & 63) == 0) red[tid >> 6] = m;
  __syncthreads();
  if (tid == 0) {
    int nw = nt >> 6;
    float M = red[0];
    for (int w = 1; w < nw; w++) M = fmaxf(M, red[w]);
    *slot = M;
  }
  __syncthreads();
  return *slot;
}

// ---------------- abs-max partials over x, w1f, w2f ----------------
__global__ void k_absmax3(const float* __restrict__ x, const float* __restrict__ w1,
                          const float* __restrict__ w2, float* __restrict__ part) {
  int seg = blockIdx.x >> 9;              // 0,1,2
  int b = blockIdx.x & 511;
  const float* p = (seg == 0) ? x : (seg == 1) ? w1 : w2;
  int i = b * 256 + threadIdx.x;
  float m = 0.f;
  #pragma unroll
  for (int it = 0; it < 8; it++) {
    f32x4 v = ((const f32x4*)p)[i + it * 131072];
    m = fmaxf(m, fmaxf(fmaxf(fabsf(v.x), fabsf(v.y)), fmaxf(fabsf(v.z), fabsf(v.w))));
  }
  for (int off = 32; off; off >>= 1) m = fmaxf(m, __shfl_down(m, off));
  __shared__ float red[4];
  if ((threadIdx.x & 63) == 0) red[threadIdx.x >> 6] = m;
  __syncthreads();
  if (threadIdx.x == 0)
    part[blockIdx.x] = fmaxf(fmaxf(red[0], red[1]), fmaxf(red[2], red[3]));
}

// ---------------- quantize + transpose a weight matrix (inline body) ----------------
__device__ __forceinline__ void quantT_body(const float* __restrict__ w, float s,
                                            i32x4* __restrict__ out, int C, int tkbits,
                                            int b) {
  int L = b * 256 + threadIdx.x;
  int h_in = L & 127;
  int kb = (L >> 7) & 3;
  int tk = (L >> 9) & ((1 << tkbits) - 1);
  int hblk = L >> (9 + tkbits);
  int h = hblk * 128 + h_in;
  int k0 = (tk * 4 + kb) * 16;
  int wd[4];
  #pragma unroll
  for (int d = 0; d < 4; d++) {
    unsigned acc = 0;
    #pragma unroll
    for (int j = 0; j < 4; j++) {
      float v = w[(size_t)(k0 + d * 4 + j) * C + h];
      int q = (int)rintf(v / s) & 255;
      acc |= (unsigned)q << (8 * j);
    }
    wd[d] = (int)acc;
  }
  i32x4 o; o.x = wd[0]; o.y = wd[1]; o.z = wd[2]; o.w = wd[3];
  out[L] = o;
}

// ---------------- fused prep: quant_x + quantT(w1) + quantT(w2) ----------------
__global__ void k_prep(const float* __restrict__ x, const float* __restrict__ w1f,
                       const float* __restrict__ w2f, const float* __restrict__ b1f,
                       const float* __restrict__ b2f, const float* __restrict__ part,
                       i32x4* __restrict__ xq, i32x4* __restrict__ w1qt,
                       i32x4* __restrict__ w2qt) {
  __shared__ float red[4];
  __shared__ float slot;
  int seg = blockIdx.x >> 10;             // block-uniform
  int b = blockIdx.x & 1023;
  if (seg == 0) {
    float s = block_absmax(part, 512, nullptr, 0, red, &slot) / 127.0f;
    int L = b * 256 + threadIdx.x;
    int m_in = L & 127, kb = (L >> 7) & 3, tk = (L >> 9) & 15, mblk = L >> 13;
    int m = mblk * 128 + m_in;
    int k0 = (tk * 4 + kb) * 16;
    const f32x4* px = (const f32x4*)(x + m * 1024 + k0);
    int wd[4];
    #pragma unroll
    for (int d = 0; d < 4; d++) {
      f32x4 v = px[d];
      int b0 = (int)rintf(v.x / s) & 255;
      int b1 = (int)rintf(v.y / s) & 255;
      int b2 = (int)rintf(v.z / s) & 255;
      int b3 = (int)rintf(v.w / s) & 255;
      wd[d] = b0 | (b1 << 8) | (b2 << 16) | (b3 << 24);
    }
    i32x4 o; o.x = wd[0]; o.y = wd[1]; o.z = wd[2]; o.w = wd[3];
    xq[L] = o;
  } else if (seg == 1) {
    float s = block_absmax(part + 512, 512, b1f, 4096, red, &slot) / 127.0f;
    quantT_body(w1f, s, w1qt, 4096, 4, b);
  } else {
    float s = block_absmax(part + 1024, 512, b2f, 1024, red, &slot) / 127.0f;
    quantT_body(w2f, s, w2qt, 1024, 6, b);
  }
}

// ---------------- GEMM1 (transposed, double-buffered): o1^T = w1q^T · x_q^T ----------------
__launch_bounds__(256)
__global__ void k_gemm1(const i32x4* __restrict__ Aq, const i32x4* __restrict__ Bq,
                        const float* __restrict__ part, const float* __restrict__ b1f,
                        unsigned* __restrict__ plane_s, unsigned* __restrict__ plane_h) {
  __shared__ i32x4 As[2][512];   // [buf][kb4][row128]
  __shared__ i32x4 Bs[2][512];
  __shared__ float red[4];
  __shared__ float slot;
  __shared__ int b1s[128];
  int tid = threadIdx.x;
  int bb = blockIdx.x;   // batch block, 0..31
  int hb = blockIdx.y;   // H block,    0..31
  int lane = tid & 63, wid = tid >> 6;
  int wm = wid & 1, wn = wid >> 1;
  int g = lane >> 4, l15 = lane & 15;

  const i32x4* gA = Aq + (size_t)hb * 16 * 512;
  const i32x4* gB = Bq + (size_t)bb * 16 * 512;

  // prefetch tile 0 into buf 0 (drains during the scale phase)
  async16(gA + tid, &As[0][tid]);
  async16(gA + tid + 256, &As[0][tid + 256]);
  async16(gB + tid, &Bs[0][tid]);
  async16(gB + tid + 256, &Bs[0][tid + 256]);

  // recompute scales from partials (bit-identical across kernels)
  float sx  = block_absmax(part, 512, nullptr, 0, red, &slot) / 127.0f;
  float s1v = block_absmax(part + 512, 512, b1f, 4096, red, &slot) / 127.0f;
  float mult1 = sx * s1v / s1v;   // exact f32 expr as reference
  for (int i = tid; i < 128; i += 256)
    b1s[i] = (int)rintf(b1f[hb * 128 + i] / s1v);

  i32x4 acc[4][4];
  #pragma unroll
  for (int r = 0; r < 4; r++)
    #pragma unroll
    for (int c = 0; c < 4; c++) acc[r][c] = (i32x4)(0);

  int abase = g * 128 + wm * 64 + l15;
  int bbase = g * 128 + wn * 64 + l15;

  for (int t = 0; t < 16; ++t) {
    int cur = t & 1;
    __syncthreads();
    if (t + 1 < 16) {
      const i32x4* ga = gA + (t + 1) * 512;
      const i32x4* gb = gB + (t + 1) * 512;
      async16(ga + tid, &As[cur ^ 1][tid]);
      async16(ga + tid + 256, &As[cur ^ 1][tid + 256]);
      async16(gb + tid, &Bs[cur ^ 1][tid]);
      async16(gb + tid + 256, &Bs[cur ^ 1][tid + 256]);
    }
    i32x4 af[4], bf[4];
    #pragma unroll
    for (int r = 0; r < 4; r++) af[r] = As[cur][abase + r * 16];
    #pragma unroll
    for (int c = 0; c < 4; c++) bf[c] = Bs[cur][bbase + c * 16];
    #pragma unroll
    for (int r = 0; r < 4; r++)
      #pragma unroll
      for (int c = 0; c < 4; c++)
        acc[r][c] = __builtin_amdgcn_mfma_i32_16x16x64_i8(af[r], bf[c], acc[r][c], 0, 0, 0);
  }

  int t2base = hb * 2 + wm;
  #pragma unroll
  for (int r = 0; r < 4; r++) {
    int hloc = wm * 64 + r * 16 + 4 * g;
    int bq0 = b1s[hloc], bq1 = b1s[hloc + 1], bq2 = b1s[hloc + 2], bq3 = b1s[hloc + 3];
    #pragma unroll
    for (int c = 0; c < 4; c++) {
      unsigned lo = 0, hi = 0;
      #pragma unroll
      for (int q = 0; q < 4; q++) {
        int y0 = acc[r][c][q];
        int bqv = (q == 0) ? bq0 : (q == 1) ? bq1 : (q == 2) ? bq2 : bq3;
        int o = (short)((int)rintf((float)y0 * mult1) + bqv);    // int16 semantics
        int a = o > 0 ? o : 0;                                   // relu
        int s8 = (int)(signed char)(a & 0xFF);
        int h8 = (a >> 8) + (s8 < 0 ? 1 : 0);                    // a = 256*h8 + s8
        lo |= (unsigned)(s8 & 0xFF) << (8 * q);
        hi |= (unsigned)(h8 & 0xFF) << (8 * q);
      }
      int m_in = wn * 64 + c * 16 + l15;
      unsigned idx = (((unsigned)(bb * 64 + t2base) * 512u + (unsigned)(r * 128 + m_in)) << 2) + g;
      plane_s[idx] = lo;
      plane_h[idx] = hi;
    }
  }
}

// ---------------- GEMM2: 64x128 tile, intra-block split-K (512 thr, 2 pipelines) ----------------
// waves 0-3: K[0,2048); waves 4-7: K[2048,4096); merge via LDS; epilogue by kh=0 waves
__launch_bounds__(512)
__global__ void k_gemm2(const i32x4* __restrict__ Ps, const i32x4* __restrict__ Ph,
                        const i32x4* __restrict__ Bq, const float* __restrict__ part,
                        const float* __restrict__ b1f, const float* __restrict__ b2f,
                        float* __restrict__ out) {
  __shared__ i32x4 st[4096];   // 64 KB: [kh][buf][ AsS 0-255 | AsH 256-511 | Bs 512-1023 ]
  // red/slot alias into buf1 of kh=0 (st[1024..2047]) — free until first buf1 prefetch
  float* red  = (float*)&st[1024];
  float* slot = red + 8;

  int tid = threadIdx.x;
  int L = blockIdx.x;
  int mb = ((L & 7) << 3) | ((L >> 3) & 7);   // same mb -> same XCD (A-strip L2 reuse)
  int nb = L >> 6;                             // 0..7
  int mblk = mb >> 1, half = mb & 1;
  int wid = tid >> 6, lane = tid & 63;
  int kh = wid >> 2, w2 = wid & 3;
  int wm = w2 & 1, wn = w2 >> 1;
  int g = lane >> 4, l15 = lane & 15;
  int t256 = tid & 255;
  int sbase = kh * 2048;
  int a_idx = (t256 >> 6) * 128 + half * 64 + (t256 & 63);

  // prefetch tt=0 into buf 0 of this kh pipeline
  {
    int t = kh * 32;
    const i32x4* pS = Ps + ((size_t)(mblk * 64 + t) << 9);
    const i32x4* pH = Ph + ((size_t)(mblk * 64 + t) << 9);
    const i32x4* pB = Bq + ((size_t)(nb * 64 + t) << 9);
    async16(pS + a_idx, &st[sbase + t256]);
    async16(pH + a_idx, &st[sbase + 256 + t256]);
    async16(pB + t256, &st[sbase + 512 + t256]);
    async16(pB + t256 + 256, &st[sbase + 768 + t256]);
  }

  // scales (overlaps tile-0 load latency)
  float s1v = block_absmax(part + 512, 512, b1f, 4096, red, slot) / 127.0f;
  float s2v = block_absmax(part + 1024, 512, b2f, 1024, red, slot) / 127.0f;
  float mult2 = s1v * s2v / s2v;   // exact f32 expr as reference
  int bq[4];
  #pragma unroll
  for (int c = 0; c < 4; c++)
    bq[c] = (int)rintf(b2f[nb * 128 + wn * 64 + c * 16 + l15] / s2v);

  i32x4 accS[2][4], accH[2][4];
  #pragma unroll
  for (int r = 0; r < 2; r++)
    #pragma unroll
    for (int c = 0; c < 4; c++) { accS[r][c] = (i32x4)(0); accH[r][c] = (i32x4)(0); }

  for (int tt = 0; tt < 32; ++tt) {
    int cur = tt & 1;
    __syncthreads();
    if (tt + 1 < 32) {
      int t = kh * 32 + tt + 1;
      const i32x4* pS = Ps + ((size_t)(mblk * 64 + t) << 9);
      const i32x4* pH = Ph + ((size_t)(mblk * 64 + t) << 9);
      const i32x4* pB = Bq + ((size_t)(nb * 64 + t) << 9);
      int R1 = sbase + (cur ^ 1) * 1024;
      async16(pS + a_idx, &st[R1 + t256]);
      async16(pH + a_idx, &st[R1 + 256 + t256]);
      async16(pB + t256, &st[R1 + 512 + t256]);
      async16(pB + t256 + 256, &st[R1 + 768 + t256]);
    }
    int R = sbase + cur * 1024;
    i32x4 aS[2], aH[2], bf[4];
    #pragma unroll
    for (int r = 0; r < 2; r++) {
      aS[r] = st[R + g * 64 + wm * 32 + r * 16 + l15];
      aH[r] = st[R + 256 + g * 64 + wm * 32 + r * 16 + l15];
    }
    #pragma unroll
    for (int c = 0; c < 4; c++) bf[c] = st[R + 512 + g * 128 + wn * 64 + c * 16 + l15];
    #pragma unroll
    for (int r = 0; r < 2; r++)
      #pragma unroll
      for (int c = 0; c < 4; c++) {
        accS[r][c] = __builtin_amdgcn_mfma_i32_16x16x64_i8(aS[r], bf[c], accS[r][c], 0, 0, 0);
        accH[r][c] = __builtin_amdgcn_mfma_i32_16x16x64_i8(aH[r], bf[c], accH[r][c], 0, 0, 0);
      }
  }

  // combine planes within this k-half (exact mod 2^32)
  int y0p[2][4][4];
  #pragma unroll
  for (int r = 0; r < 2; r++)
    #pragma unroll
    for (int c = 0; c < 4; c++)
      #pragma unroll
      for (int q = 0; q < 4; q++)
        y0p[r][c][q] = accS[r][c][q] + accH[r][c][q] * 256;

  __syncthreads();                 // staging LDS now dead; reuse as merge buffer
  int* mg = (int*)st;              // 32 KB: [idx32][t256]
  if (kh == 1) {
    #pragma unroll
    for (int r = 0; r < 2; r++)
      #pragma unroll
      for (int c = 0; c < 4; c++)
        #pragma unroll
        for (int q = 0; q < 4; q++)
          mg[((r * 4 + c) * 4 + q) * 256 + t256] = y0p[r][c][q];
  }
  __syncthreads();
  if (kh == 0) {
    #pragma unroll
    for (int r = 0; r < 2; r++) {
      int m0 = mb * 64 + wm * 32 + r * 16 + 4 * g;
      #pragma unroll
      for (int c = 0; c < 4; c++) {
        int n = nb * 128 + wn * 64 + c * 16 + l15;
        #pragma unroll
        for (int q = 0; q < 4; q++) {
          int y0 = y0p[r][c][q] + mg[((r * 4 + c) * 4 + q) * 256 + t256];
          int o = (short)((int)rintf((float)y0 * mult2) + bq[c]);   // int16 semantics
          out[(size_t)(m0 + q) * 1024 + n] = (float)o * s2v;
        }
      }
    }
  }
}

extern "C" void kernel_launch(void* const* d_in, const int* in_sizes, int n_in,
                              void* d_out, int out_size, void* d_ws, size_t ws_size,
                              hipStream_t stream) {
  const float* x   = (const float*)d_in[0];
  const float* w1f = (const float*)d_in[1];
  const float* b1f = (const float*)d_in[2];
  const float* w2f = (const float*)d_in[3];
  const float* b2f = (const float*)d_in[4];
  float* out = (float*)d_out;

  char* ws = (char*)d_ws;
  float*  part    = (float*)(ws + WS_PART);
  i32x4*  xq      = (i32x4*)(ws + WS_XQ);
  i32x4*  w1qt    = (i32x4*)(ws + WS_W1QT);
  i32x4*  w2qt    = (i32x4*)(ws + WS_W2QT);
  unsigned* ps    = (unsigned*)(ws + WS_PS);
  unsigned* ph    = (unsigned*)(ws + WS_PH);

  k_absmax3<<<1536, 256, 0, stream>>>(x, w1f, w2f, part);
  k_prep<<<3072, 256, 0, stream>>>(x, w1f, w2f, b1f, b2f, part, xq, w1qt, w2qt);
  k_gemm1<<<dim3(32, 32), 256, 0, stream>>>(w1qt, xq, part, b1f, ps, ph);
  k_gemm2<<<512, 512, 0, stream>>>((const i32x4*)ps, (const i32x4*)ph, w2qt,
                                   part, b1f, b2f, out);
}